// Round 17
// baseline (18.203 us; speedup 1.0000x reference)
//
#include <hip/hip_runtime.h>
#include <math.h>

// ECT layer: ect[b,t,r] = sum_{n: batch[n]==b} sigmoid(8*(lin[r] - <x_n,v_t>))
// N=100000, D=3, T=64, R=64, B=128, lin = linspace(-1.1,1.1,64), d = 2.2/63.
//
// Validated core (r4-r16): CIC-deposit nh onto lin-aligned grid (bins 63..221
// at scale 256, pad 63 below), convolve with compile-time sigmoid taps;
// 64 saturated taps folded into a register suffix-scan window (J0=64).
// r7: u32 LDS atomics (f32 LDS atomics = slow serial FP-RMW on gfx950, 4x).
// r11: extra dispatch ~3-5us -> single dispatch. r13/r14: 16-bit-packed
// atomics + integer bin math. r15/r16: TPB=8 and bank-stagger both neutral.
//
// Round-17 (DS-pipe budget: conv 4.3us + scan 2.4us dominate; ramp 1.5us):
//  - conv: 40 ds_read2_b32 -> 20 ds_read2_b64 (4 taps/instr). Even lanes
//    read Hf (base r+64 even -> 8B aligned); odd lanes read a SHIFTED copy
//    Hfs[a]=H[a+1] (base r+63 even -> aligned), built with 3 extra ds_writes
//    per row-wave. Same literal tap weights for all lanes.
//  - search: 2-round 64-lane vector probe of the +-1024 window (stride 32
//    gather + ballot -> <=32 bracket; stride 1 -> exact) replaces the 11-deep
//    dependent scalar chain. Window validated by 2 edge loads; full-range
//    scalar fallback -> unconditionally correct.
//  - base config: TPB=4, TQ=16 (r14 = measured best).

#define THREADS 256
#define TPB 4              // directions per block (1 per wave)
#define TQ  16             // blocks per point cloud
#define J0  64             // taps j<J0 == 1.0 exactly (window via scan)
#define STEPS 144          // real taps j in [J0,STEPS): 80 literal fmas
#define ROWW 128           // u32 words per row per parity array
#define HO_BASE (TPB * ROWW)            // Ho offset in u32 words (512)
#define HF_BASE (2 * TPB * ROWW)        // Hf (f32) offset in words (1024)
#define HFS_BASE (HF_BASE + TPB * 256)  // shifted Hf copy (2048)
#define ROW32 256          // f32 elements per row in conv buffers
#define BSEG 128

#if __has_builtin(__builtin_amdgcn_fmed3f)
#define CLAMP(v, lo, hi) __builtin_amdgcn_fmed3f((v), (lo), (hi))
#else
#define CLAMP(v, lo, hi) fminf(fmaxf((v), (lo)), (hi))
#endif

typedef float f2 __attribute__((ext_vector_type(2)));

// ---- compile-time sigmoid tap table (folds the 2^-8 quanta unscale) ----
constexpr double cexp_taylor(double r) {
    double s = 1.0, term = 1.0;
    for (int i = 1; i < 18; ++i) { term *= r / (double)i; s += term; }
    return s;
}
constexpr double cexp(double x) {
    const double LN2 = 0.69314718055994530942;
    const int n = (int)(x / LN2 + (x >= 0.0 ? 0.5 : -0.5));
    const double r = x - (double)n * LN2;
    double e = cexp_taylor(r);
    if (n >= 0) { for (int i = 0; i < n;  ++i) e *= 2.0; }
    else        { for (int i = 0; i < -n; ++i) e *= 0.5; }
    return e;
}
struct WTab {
    float w[STEPS];
    constexpr WTab() : w() {
        const double d = 2.2 / 63.0;
        for (int j = 0; j < STEPS; ++j) {
            const double z = 8.0 * d * (double)(111 - j);
            w[j] = (float)(1.0 / ((1.0 + cexp(-z)) * 256.0));
        }
    }
};
constexpr WTab WT;

// inclusive suffix sum within a 64-lane wave
__device__ __forceinline__ float wave_suffix(float x, int lane) {
#pragma unroll
    for (int d = 1; d < 64; d <<= 1) {
        const float y = __shfl_down(x, d, 64);
        x += (lane + d < 64) ? y : 0.0f;
    }
    return x;
}

// full-range scalar lower_bound (fallback only)
__device__ __forceinline__ int lower_fallback(const int* __restrict__ A,
                                              int n, int val) {
    int lo = 0, hi = n;
    while (hi > lo) {
        const int mid = (lo + hi) >> 1;
        const int key = A[__builtin_amdgcn_readfirstlane(mid)];
        if (key < val) lo = mid + 1; else hi = mid;
    }
    return lo;
}

// 2-round vectorized lower_bound over the +-1024 expected-position window.
// Window validated by 2 edge loads; sets *bad (wave-uniform) on violation.
__device__ __forceinline__ int lower_vec(const int* __restrict__ A, int n,
                                         int val, int lane, bool* bad) {
    const long long g = ((long long)val * (long long)n) >> 7;   // val*n/128
    int wlo = (int)g - 1024; if (wlo < 0) wlo = 0;
    int whi = (int)g + 1024; if (whi > n) whi = n;
    // validation edges (uniform) + round-1 gather (stride 32)
    const bool okl = (wlo == 0) || (A[wlo - 1] < val);
    const bool okh = (whi == n) || (A[whi] >= val);
    const int p  = wlo + (lane << 5);
    const int pc = (p < whi) ? p : (whi - 1);
    const unsigned long long m1 = __ballot((p < whi) && (A[pc] < val));
    if (!(okl && okh)) { *bad = true; return 0; }
    const int c1 = __popcll(m1);                 // prefix length (A sorted)
    if (c1 == 0) return wlo;                     // A[wlo] >= val, edge valid
    const int lo2 = wlo + ((c1 - 1) << 5) + 1;   // A[lo2-1] < val
    int hi2 = wlo + (c1 << 5); if (hi2 > whi) hi2 = whi;   // A[hi2] >= val
    const int w  = hi2 - lo2;                    // bracket width 0..31
    const int q  = lo2 + lane;
    const int qc = (q < n) ? q : (n - 1);
    const unsigned long long m2 = __ballot((lane < w) && (A[qc] < val));
    return lo2 + __popcll(m2);
}

__global__ __launch_bounds__(THREADS, 8) void ect_fused14_kernel(
    const float* __restrict__ x,      // [N,3]
    const float* __restrict__ v,      // [3,64]
    const int*   __restrict__ batch,  // [N] sorted 0..127
    float* __restrict__ out,          // [128,64,64]
    int n, float inv_d256, float bias256)
{
    // [He: 512 u32][Ho: 512 u32][Hf: 1024 f32][Hfs: 1024 f32] = 12 KiB
    __shared__ unsigned Ls[HFS_BASE + TPB * ROW32];

    const int tid  = threadIdx.x;
    const int wv   = tid >> 6;
    const int lane = tid & 63;
    const int b    = blockIdx.x >> 4;            // / TQ
    const int tq   = blockIdx.x & (TQ - 1);

    // zero the packed histograms (1024 u32 = 512 u64; Hf/Hfs fully written)
    {
        unsigned long long* z = (unsigned long long*)Ls;
        for (int i = tid; i < TPB * ROWW; i += THREADS) z[i] = 0ull;
    }

    // segment bounds: 2-round vector searches (fallback: scalar full range)
    bool bad = false;
    int s0 = lower_vec(batch, n, b,     lane, &bad);
    int s1 = lower_vec(batch, n, b + 1, lane, &bad);
    if (bad) {
        s0 = lower_fallback(batch, n, b);
        s1 = lower_fallback(batch, n, b + 1);
    }

    // deposit mapping: lane = (t_l 0..3, slot 0..15); block = 64 nodes/iter
    const int t_l  = lane >> 4;
    const int slot = (lane & 15) + (wv << 4);    // 0..63 across waves
    const int tbase = tq * TPB;
    const int t    = tbase + t_l;
    const float va = v[t], vb = v[64 + t], vc = v[128 + t];
    const int rowbyte = t_l << 9;                // t_l * 512 B

    __syncthreads();                             // barrier 1: zero done

    // deposit one (node,dir): ~13 VALU + 1 ds_add_u32.
    // a = ufix>>8 in [63,221]; (a,a+1): even a -> He[a>>1], odd -> Ho[a>>1].
#define DEPOSIT(x0, x1, x2)                                                   \
    {                                                                         \
        const float nh = fmaf((x0), va, fmaf((x1), vb, (x2) * vc));           \
        float bf = fmaf(nh, inv_d256, bias256);                               \
        bf = CLAMP(bf, 16128.0f, 56831.0f);      /* a in [63, 221] */         \
        const unsigned ufix = (unsigned)bf;                                   \
        const unsigned q1   = ufix & 255u;                                    \
        const unsigned val  = (q1 << 16) + (256u - q1);                       \
        const unsigned wbyte = ((ufix >> 7) & ~3u)                            \
                             + ((ufix & 256u) ? (HO_BASE << 2) : 0u)          \
                             + (unsigned)rowbyte;                             \
        atomicAdd((unsigned*)((char*)Ls + wbyte), val);                       \
    }

    // ---- phase 1: CIC deposit; full 256-node chunks guard-free + tail ----
    {
        const int len = s1 - s0;
        const int nfull = len >> 8;
        int base = s0;
        for (int c = 0; c < nfull; ++c, base += 256) {
            float xs[4][3];
#pragma unroll
            for (int k = 0; k < 4; ++k) {
                const float3 xx = *(const float3*)(x + 3 * (size_t)(base + (k << 6) + slot));
                xs[k][0] = xx.x; xs[k][1] = xx.y; xs[k][2] = xx.z;
            }
#pragma unroll
            for (int k = 0; k < 4; ++k) DEPOSIT(xs[k][0], xs[k][1], xs[k][2]);
        }
        for (; base < s1; base += 64) {
            const int idx = base + slot;
            if (idx < s1) {
                const float3 xx = *(const float3*)(x + 3 * (size_t)idx);
                DEPOSIT(xx.x, xx.y, xx.z);
            }
        }
    }

    __syncthreads();                             // barrier 2: deposits done

    // ---- phase 1.5: reconstruct H (u16 halves -> f32), wave owns row wv ----
    // H[a] = He.half[a] + Ho.half[a-1]; writes Hf[a] and shifted Hfs[a-1].
    float c[4];
    {
        const unsigned* He = Ls + wv * ROWW;
        const unsigned* Ho = Ls + HO_BASE + wv * ROWW;
        float* Hf  = (float*)(Ls + HF_BASE)  + wv * ROW32;
        float* Hfs = (float*)(Ls + HFS_BASE) + wv * ROW32;
        const int par = lane & 1;
#pragma unroll
        for (int q = 0; q < 4; ++q) {
            const int a = lane + 64 * q;
            const unsigned heW = He[a >> 1];
            const unsigned he  = par ? (heW >> 16) : (heW & 0xFFFFu);
            unsigned ho = 0u;
            if (a > 0) {                          // uniform except lane0,q0
                const unsigned hoW = Ho[(a - 1) >> 1];
                ho = par ? (hoW & 0xFFFFu) : (hoW >> 16);
            }
            c[q] = (float)(he + ho);
            if (q > 0) { Hf[a] = c[q]; Hfs[a - 1] = c[q]; }
        }
    }

    // ---- phase 1.75: register suffix scan; 64-tap window in-register ----
    float tot23 = c[2] + c[3];
#pragma unroll
    for (int d = 1; d < 64; d <<= 1) tot23 += __shfl_xor(tot23, d, 64);
    const float s1v   = wave_suffix(c[1], lane) + tot23;
    const float carry = __shfl(s1v, 0, 64);
    const float s0v   = wave_suffix(c[0], lane) + carry;
    const float window = (s0v - s1v) * (1.0f / 256.0f);

    __syncthreads();   // barrier 3: Hf/Hfs visible to cross-lane conv reads

    // ---- phase 2: conv, 80 literal taps via 20 ds_read2_b64 ----
    // even lane r: base Hf + r+64 (8B aligned); odd lane r: base Hfs + r+63
    // (Hfs[a] = H[a+1] -> same tap sequence, aligned).
    const int odd = lane & 1;
    const float* Hb = (const float*)(Ls + (odd ? HFS_BASE : HF_BASE))
                      + wv * ROW32 + lane + 64 - odd;
    const f2* H2 = (const f2*)Hb;                // 8B-aligned
    float a0 = window, a1 = 0.f, a2 = 0.f, a3 = 0.f;
#pragma unroll
    for (int k = 0; k < (STEPS - J0) / 4; ++k) {
        const f2 u = H2[2 * k];                  // taps j=64+4k, 65+4k
        const f2 w2 = H2[2 * k + 1];             // taps j=66+4k, 67+4k
        a0 = fmaf(WT.w[J0 + 4 * k],     u.x,  a0);
        a1 = fmaf(WT.w[J0 + 4 * k + 1], u.y,  a1);
        a2 = fmaf(WT.w[J0 + 4 * k + 2], w2.x, a2);
        a3 = fmaf(WT.w[J0 + 4 * k + 3], w2.y, a3);
    }
    out[((size_t)b * 64 + tbase + wv) * 64 + lane] = (a0 + a1) + (a2 + a3);
#undef DEPOSIT
}

extern "C" void kernel_launch(void* const* d_in, const int* in_sizes, int n_in,
                              void* d_out, int out_size, void* d_ws, size_t ws_size,
                              hipStream_t stream) {
    const float* x     = (const float*)d_in[0];
    const float* v     = (const float*)d_in[1];
    const int*   batch = (const int*)d_in[2];
    float*       out   = (float*)d_out;

    const int n = in_sizes[0] / 3;

    const double d = 2.2 / 63.0;
    const float inv_d256 = (float)(256.0 / d);         // bin scale 256
    const float bias256  = (79.5f + 63.0f) * 256.0f;   // 36480: pad included

    hipLaunchKernelGGL(ect_fused14_kernel, dim3(BSEG * TQ), dim3(THREADS), 0,
                       stream, x, v, batch, out, n, inv_d256, bias256);
}

// Round 18
// 16.229 us; speedup vs baseline: 1.1216x; 1.1216x over previous
//
#include <hip/hip_runtime.h>
#include <math.h>

// ECT layer: ect[b,t,r] = sum_{n: batch[n]==b} sigmoid(8*(lin[r] - <x_n,v_t>))
// N=100000, D=3, T=64, R=64, B=128, lin = linspace(-1.1,1.1,64), d = 2.2/63.
//
// FINAL (= r14, best measured 16.15us). Validated findings embodied here:
//  - CIC-deposit nh onto a lin-aligned grid (bins 63..221 at scale 256,
//    63-bin zero pad below), then convolve with the exact sigmoid taps.
//    Linear-split error <= sig''*d^2/8 ~ 9.4e-4/node << threshold.
//  - r7: f32 LDS atomics are a slow serial FP-RMW path on gfx950; u32
//    atomics are ~4x faster. Deposits are 16-bit-packed u32 (q1=round
//    (fr*256), q0=256-q1) into parity-staggered arrays He/Ho so each
//    (a,a+1) pair is ONE ds_add_u32.
//  - r8: taps are compile-time constants -> 80 literal v_fmac + ds_read2;
//    64 saturated taps (==1.0) folded into a register suffix-scan window.
//  - r11: every extra dispatch costs ~3-5us -> single dispatch; segment
//    bounds via windowed scalar binary search (expected position +-1024,
//    edge-validated, full-range fallback -> unconditionally correct).
//  - r14: integer bin math (fma->fmed3->cvt, bit-field address), guard-free
//    deposit main loop.
// Post-r14 attempts all neutral/negative: TPB=8 (r15), bank-stagger (r16),
// ds_read2_b64 conv + vector search (r17). Wall ~16us = distributed floor:
// conv ~3-4us DS + scan ~1.6 + deposit ~2 + launch ~2.5 + ramp/drain ~3.

#define THREADS 256
#define TPB 4              // directions per block (1 per wave)
#define TQ  16             // blocks per point cloud
#define J0  64             // taps j<J0 == 1.0 exactly (window via scan)
#define STEPS 144          // real taps j in [J0,STEPS): 80 literal fmas
#define ROWW 128           // u32 words per row per parity array
#define HO_BASE (TPB * ROWW)            // Ho offset in u32 words (512)
#define HF_BASE (2 * TPB * ROWW)        // f32 H region offset (1024)
#define ROW32 256          // f32 elements per row in conv buffer
#define BSEG 128

#if __has_builtin(__builtin_amdgcn_fmed3f)
#define CLAMP(v, lo, hi) __builtin_amdgcn_fmed3f((v), (lo), (hi))
#else
#define CLAMP(v, lo, hi) fminf(fmaxf((v), (lo)), (hi))
#endif

// ---- compile-time sigmoid tap table (folds the 2^-8 quanta unscale) ----
constexpr double cexp_taylor(double r) {
    double s = 1.0, term = 1.0;
    for (int i = 1; i < 18; ++i) { term *= r / (double)i; s += term; }
    return s;
}
constexpr double cexp(double x) {
    const double LN2 = 0.69314718055994530942;
    const int n = (int)(x / LN2 + (x >= 0.0 ? 0.5 : -0.5));
    const double r = x - (double)n * LN2;
    double e = cexp_taylor(r);
    if (n >= 0) { for (int i = 0; i < n;  ++i) e *= 2.0; }
    else        { for (int i = 0; i < -n; ++i) e *= 0.5; }
    return e;
}
struct WTab {
    float w[STEPS];
    constexpr WTab() : w() {
        const double d = 2.2 / 63.0;
        for (int j = 0; j < STEPS; ++j) {
            const double z = 8.0 * d * (double)(111 - j);
            w[j] = (float)(1.0 / ((1.0 + cexp(-z)) * 256.0));
        }
    }
};
constexpr WTab WT;

// inclusive suffix sum within a 64-lane wave
__device__ __forceinline__ float wave_suffix(float x, int lane) {
#pragma unroll
    for (int d = 1; d < 64; d <<= 1) {
        const float y = __shfl_down(x, d, 64);
        x += (lane + d < 64) ? y : 0.0f;
    }
    return x;
}

// uniform scalar lower_bound, +-1024 window around expected position
// (validated by 2 loads; falls back to [0,n) -> unconditionally correct)
__device__ __forceinline__ int lower_scalar(const int* __restrict__ A, int n,
                                            int val) {
    const long long g = ((long long)val * (long long)n) >> 7;
    int lo = (int)(g - 1024 > 0 ? g - 1024 : 0);
    int hi = (int)(g + 1024 < n ? g + 1024 : n);
    const bool okl = (lo == 0) || (A[__builtin_amdgcn_readfirstlane(lo - 1)] < val);
    const bool okh = (hi == n) || (A[__builtin_amdgcn_readfirstlane(hi)] >= val);
    if (!(okl && okh)) { lo = 0; hi = n; }
    while (hi > lo) {
        const int mid = (lo + hi) >> 1;
        const int key = A[__builtin_amdgcn_readfirstlane(mid)];
        if (key < val) lo = mid + 1; else hi = mid;
    }
    return lo;
}

__global__ __launch_bounds__(THREADS, 8) void ect_final_kernel(
    const float* __restrict__ x,      // [N,3]
    const float* __restrict__ v,      // [3,64]
    const int*   __restrict__ batch,  // [N] sorted 0..127
    float* __restrict__ out,          // [128,64,64]
    int n, float inv_d256, float bias256)
{
    // [He: 512 u32][Ho: 512 u32][Hf: 1024 f32] = 8 KiB
    __shared__ unsigned Ls[2 * TPB * ROWW + TPB * ROW32];

    const int tid  = threadIdx.x;
    const int wv   = tid >> 6;
    const int lane = tid & 63;
    const int b    = blockIdx.x >> 4;
    const int tq   = blockIdx.x & (TQ - 1);

    // zero the packed histograms (1024 u32 = 4KB; Hf overwritten later)
    {
        unsigned long long* z = (unsigned long long*)Ls;
        for (int i = tid; i < TPB * ROWW; i += THREADS) z[i] = 0ull;
    }

    // segment bounds: two scalar s_load chains, overlapped with zeroing
    const int s0 = lower_scalar(batch, n, b);
    const int s1 = lower_scalar(batch, n, b + 1);

    // deposit mapping: lane = (t_l, slot)
    const int t_l  = lane >> 4;
    const int slot = (lane & 15) + (wv << 4);
    const int tbase = tq * TPB;
    const int t    = tbase + t_l;
    const float va = v[t], vb = v[64 + t], vc = v[128 + t];
    const int rowbyte = (t_l * ROWW) << 2;       // byte offset of He row t_l

    __syncthreads();                             // barrier 1: zero done

    // deposit one (node,dir): ~13 VALU + 1 ds_add_u32
    // a = ufix>>8 in [63,221]; (a,a+1): even a -> He[a>>1], odd -> Ho[a>>1]
#define DEPOSIT(x0, x1, x2)                                                   \
    {                                                                         \
        const float nh = fmaf((x0), va, fmaf((x1), vb, (x2) * vc));           \
        float bf = fmaf(nh, inv_d256, bias256);                               \
        bf = CLAMP(bf, 16128.0f, 56831.0f);      /* a in [63, 221] */         \
        const unsigned ufix = (unsigned)bf;      /* a=ufix>>8, fr8=ufix&255 */\
        const unsigned q1   = ufix & 255u;                                    \
        const unsigned val  = (q1 << 16) + (256u - q1);                       \
        const unsigned wbyte = ((ufix >> 7) & ~3u)        /* (a>>1)<<2 */     \
                             + ((ufix & 256u) ? (HO_BASE << 2) : 0u)          \
                             + (unsigned)rowbyte;                             \
        atomicAdd((unsigned*)((char*)Ls + wbyte), val);                       \
    }

    // ---- phase 1: CIC deposit; full 256-node chunks guard-free + tail ----
    {
        const int len = s1 - s0;
        const int nfull = len >> 8;
        int base = s0;
        for (int c = 0; c < nfull; ++c, base += 256) {
            float xs[4][3];
#pragma unroll
            for (int k = 0; k < 4; ++k) {
                const float3 xx = *(const float3*)(x + 3 * (size_t)(base + (k << 6) + slot));
                xs[k][0] = xx.x; xs[k][1] = xx.y; xs[k][2] = xx.z;
            }
#pragma unroll
            for (int k = 0; k < 4; ++k) DEPOSIT(xs[k][0], xs[k][1], xs[k][2]);
        }
        for (; base < s1; base += 64) {
            const int idx = base + slot;
            if (idx < s1) {
                const float3 xx = *(const float3*)(x + 3 * (size_t)idx);
                DEPOSIT(xx.x, xx.y, xx.z);
            }
        }
    }

    __syncthreads();                             // barrier 2: deposits done

    // ---- phase 1.5: reconstruct H (u16 halves -> f32), wave owns row wv ----
    // H[a] = He.half[a] + Ho.half[a-1]:
    //   a even: He[a>>1].lo + (a>0 ? Ho[(a>>1)-1].hi : 0)
    //   a odd : Ho[a>>1].lo + He[a>>1].hi
    float c[4];
    {
        const unsigned* He = Ls + wv * ROWW;
        const unsigned* Ho = Ls + HO_BASE + wv * ROWW;
        float* Hf = (float*)(Ls + HF_BASE) + wv * ROW32;
        const int par = lane & 1;
#pragma unroll
        for (int q = 0; q < 4; ++q) {
            const int a = lane + 64 * q;
            const unsigned heW = He[a >> 1];
            const unsigned he  = par ? (heW >> 16) : (heW & 0xFFFFu);
            unsigned ho = 0u;
            if (a > 0) {                          // uniform except lane0,q0
                const unsigned hoW = Ho[(a - 1) >> 1];
                ho = par ? (hoW & 0xFFFFu) : (hoW >> 16);
            }
            c[q] = (float)(he + ho);
            if (q > 0) Hf[a] = c[q];              // conv reads a in [64,208)
        }
    }

    // ---- phase 1.75: register suffix scan; 64-tap window in-register ----
    float tot23 = c[2] + c[3];
#pragma unroll
    for (int d = 1; d < 64; d <<= 1) tot23 += __shfl_xor(tot23, d, 64);
    const float s1v   = wave_suffix(c[1], lane) + tot23;
    const float carry = __shfl(s1v, 0, 64);
    const float s0v   = wave_suffix(c[0], lane) + carry;
    const float window = (s0v - s1v) * (1.0f / 256.0f);

    __syncthreads();   // barrier 3: Hf visible to cross-lane conv reads
                       // (required: compiler may hoist per-thread-disjoint
                       //  ds_reads above other lanes' ds_writes - r10 lesson)

    // ---- phase 2: conv, 80 literal-fma taps, 40 ds_read2 ----
    const float* H = (const float*)(Ls + HF_BASE) + wv * ROW32 + lane;
    float a0 = window, a1 = 0.f;
#pragma unroll
    for (int j = J0; j < STEPS; j += 2) {
        a0 = fmaf(WT.w[j],     H[j],     a0);
        a1 = fmaf(WT.w[j + 1], H[j + 1], a1);
    }
    out[((size_t)b * 64 + tbase + wv) * 64 + lane] = a0 + a1;
#undef DEPOSIT
}

extern "C" void kernel_launch(void* const* d_in, const int* in_sizes, int n_in,
                              void* d_out, int out_size, void* d_ws, size_t ws_size,
                              hipStream_t stream) {
    const float* x     = (const float*)d_in[0];
    const float* v     = (const float*)d_in[1];
    const int*   batch = (const int*)d_in[2];
    float*       out   = (float*)d_out;

    const int n = in_sizes[0] / 3;

    const double d = 2.2 / 63.0;
    const float inv_d256 = (float)(256.0 / d);         // bin scale 256
    const float bias256  = (79.5f + 63.0f) * 256.0f;   // 36480: pad included

    hipLaunchKernelGGL(ect_final_kernel, dim3(BSEG * TQ), dim3(THREADS), 0,
                       stream, x, v, batch, out, n, inv_d256, bias256);
}